// Round 15
// baseline (452.751 us; speedup 1.0000x reference)
//
#include <hip/hip_runtime.h>
#include <hip/hip_bf16.h>
#include <stdint.h>

// Problem constants (PrismEncoder)
#define B_   128
#define N1_  256
#define N2_  256
#define D_   256
#define H_   8
#define DH_  32
#define DFF_ 1024
#define M_   (B_*N1_)   // 32768 rows

typedef unsigned short ushortT;
typedef unsigned int   uintT;
typedef short bf16x8 __attribute__((ext_vector_type(8)));
typedef float f32x4  __attribute__((ext_vector_type(4)));

#if __has_builtin(__builtin_amdgcn_exp2f)
#define EXP2(x) __builtin_amdgcn_exp2f(x)
#else
#define EXP2(x) exp2f(x)
#endif

__device__ __forceinline__ float b2f(ushortT u){ return __uint_as_float(((uintT)u)<<16); }
__device__ __forceinline__ ushortT f2b(float f){
  uintT u = __float_as_uint(f);
  uintT r = (u + 0x7fffu + ((u>>16)&1u)) >> 16;   // RNE
  return (ushortT)r;
}

// Dtype sniff, wave-parallel.
__device__ __forceinline__ int sniff_wave(const ushortT* x){
  const int e = (x[threadIdx.x & 63] >> 7) & 0xff;
  const unsigned long long bad = __ballot(e < 100 || e > 135);
  return __popcll(bad) >= 12;
}
__device__ __forceinline__ float ldin(const void* p, size_t i, int f32){
  return f32 ? ((const float*)p)[i] : b2f(((const ushortT*)p)[i]);
}

// Load 8 contiguous A elements as bf16x8-packed uint4, converting from f32
// inline when needed (saves the separate conversion pass + round-trip).
template<int F32>
__device__ __forceinline__ uint4 ldA8(const void* A, size_t e){
  if (F32) {
    const float* p = (const float*)A + e;
    const float4 a = *(const float4*)p;
    const float4 b = *(const float4*)(p + 4);
    uint4 r;
    r.x = (uintT)f2b(a.x) | ((uintT)f2b(a.y) << 16);
    r.y = (uintT)f2b(a.z) | ((uintT)f2b(a.w) << 16);
    r.z = (uintT)f2b(b.x) | ((uintT)f2b(b.y) << 16);
    r.w = (uintT)f2b(b.z) | ((uintT)f2b(b.w) << 16);
    return r;
  } else {
    return *(const uint4*)((const ushortT*)A + e);
  }
}

// ---------------------------------------------------------------------------
// 32x32 transpose tile body (shared array passed in; barrier is uniform
// per-block since callers branch on blockIdx only).
// ---------------------------------------------------------------------------
__device__ __forceinline__ void tw_body(
    const void* W, ushortT* Wt, int K, int N, int xb, int yb, int in_f32,
    float (*t)[33])
{
  const int tx = threadIdx.x & 31, ty = threadIdx.x >> 5;  // ty 0..7
  const int n0 = xb * 32, k0 = yb * 32;
  #pragma unroll
  for (int i = 0; i < 4; i++)
    t[ty + 8*i][tx] = ldin(W, (size_t)(k0 + ty + 8*i) * N + n0 + tx, in_f32);
  __syncthreads();
  #pragma unroll
  for (int i = 0; i < 4; i++)
    Wt[(size_t)(n0 + ty + 8*i) * K + k0 + tx] = f2b(t[tx][ty + 8*i]);
}

// ---------------------------------------------------------------------------
// PREP (single dispatch, 1800 blocks): adjacency+mask bit-pack, Wk|Wv|Wq|Wo
// -> S5 pack, W1t, W2t. All independent.
//   [0,1024)    adj pack    [1024,1032) mask pack
//   [1032,1288) w4 256x256  [1288,1544) W1t (32x8)  [1544,1800) W2t (8x32)
// ---------------------------------------------------------------------------
__global__ __launch_bounds__(256) void prep_kernel(
    const void* __restrict__ ADJ, uintT* __restrict__ AB,
    const void* __restrict__ M1, const void* __restrict__ M2,
    uintT* __restrict__ MW,
    const void* __restrict__ Wk, const void* __restrict__ Wv,
    const void* __restrict__ Wq, const void* __restrict__ Wo,
    ushortT* __restrict__ Wpack,
    const void* __restrict__ W1, ushortT* __restrict__ W1t,
    const void* __restrict__ W2, ushortT* __restrict__ W2t,
    const ushortT* __restrict__ sniffp)
{
  __shared__ float t[32][33];
  const int in_f32 = sniff_wave(sniffp);
  const int bid = blockIdx.x;

  if (bid < 1024) {
    const int idx = bid * 256 + threadIdx.x;               // 262144 words
    const size_t base = (size_t)(idx >> 3) * 256 + (size_t)(idx & 7) * 32;
    uintT bits = 0;
    if (in_f32) {
      const float* ap = (const float*)ADJ + base;
      #pragma unroll
      for (int j4 = 0; j4 < 8; j4++) {
        float4 v = *(const float4*)(ap + j4 * 4);
        bits |= (v.x > 0.f ? 1u : 0u) << (j4 * 4 + 0);
        bits |= (v.y > 0.f ? 1u : 0u) << (j4 * 4 + 1);
        bits |= (v.z > 0.f ? 1u : 0u) << (j4 * 4 + 2);
        bits |= (v.w > 0.f ? 1u : 0u) << (j4 * 4 + 3);
      }
    } else {
      const ushortT* ap = (const ushortT*)ADJ + base;
      #pragma unroll
      for (int j = 0; j < 32; j++)
        bits |= (b2f(ap[j]) > 0.f ? 1u : 0u) << j;
    }
    AB[idx] = bits;
    return;
  }
  if (bid < 1032) {
    const int idx = (bid - 1024) * 256 + threadIdx.x;      // 2048 words
    const int src = idx >> 10;
    const void* MP = src ? M2 : M1;
    const size_t base = (size_t)((idx >> 3) & 127) * 256 + (size_t)(idx & 7) * 32;
    uintT bits = 0;
    #pragma unroll
    for (int j = 0; j < 32; j++)
      bits |= (ldin(MP, base + j, in_f32) > 0.f ? 1u : 0u) << j;
    MW[idx] = bits;
    return;
  }
  if (bid < 1288) {
    const int idx = bid - 1032;                            // 256: 8x8x4
    const int z = idx >> 6, yb = (idx >> 3) & 7, xb = idx & 7;
    const void* W = (z == 0) ? Wk : (z == 1) ? Wv : (z == 2) ? Wq : Wo;
    tw_body(W, Wpack + (size_t)z * 65536, 256, 256, xb, yb, in_f32, t);
    return;
  }
  if (bid < 1544) {
    const int idx = bid - 1288;                            // 256: 32x8
    tw_body(W1, W1t, 256, 1024, idx & 31, idx >> 5, in_f32, t);
    return;
  }
  {
    const int idx = bid - 1544;                            // 256: 8x32
    tw_body(W2, W2t, 1024, 256, idx & 7, idx >> 3, in_f32, t);
  }
}

// ---------------------------------------------------------------------------
// MFMA GEMM v5 (proven best): 128x128 tile, 2x2 waves, 4x4 16x16x32 frags,
// BK=32, LDS stride 40 (2-way free), VGPR prefetch, XCD swizzle (pow2 gy).
// C = (A[M,K] @ Bt[N,K]^T + bias) * alpha, relu. bf16 A only (hot-path
// GEMMs all read bf16 intermediates).
// ---------------------------------------------------------------------------
__global__ __launch_bounds__(256) void gemm128_kernel(
    const ushortT* __restrict__ A, const ushortT* __restrict__ Bt,
    const void* __restrict__ bias, ushortT* __restrict__ C,
    int M, int N, int K, int relu, float alpha,
    const ushortT* __restrict__ sniffp)
{
  __shared__ ushortT Al[128 * 40];
  __shared__ ushortT Bl[128 * 40];

  const int tid = threadIdx.x;
  const int in_f32 = sniff_wave(sniffp);
  const int wave = tid >> 6, lane = tid & 63;
  const int l15 = lane & 15, l4 = lane >> 4;
  const int wm = wave & 1, wn = wave >> 1;

  const int lin = blockIdx.x + gridDim.x * blockIdx.y;
  const int chunk = (gridDim.x * gridDim.y) >> 3;
  const int gsw = (lin & 7) * chunk + (lin >> 3);
  const int ylog = 31 - __clz(gridDim.y);
  const int bx = gsw >> ylog, by = gsw & (gridDim.y - 1);
  const int row0 = bx * 128, col0 = by * 128;
  const int m0 = wm * 64, n0 = wn * 64;

  f32x4 acc[4][4];
  #pragma unroll
  for (int i = 0; i < 4; i++)
    #pragma unroll
    for (int j = 0; j < 4; j++) acc[i][j] = (f32x4)0.f;

  const int sr = tid >> 2;          // 0..63
  const int sk = (tid & 3) * 8;     // 0,8,16,24

  const ushortT* Ap = &A[(size_t)(row0 + sr) * K + sk];
  const ushortT* Bp = &Bt[(size_t)(col0 + sr) * K + sk];
  const size_t step64 = (size_t)64 * K;

  uint4 a0 = *(const uint4*)Ap;
  uint4 a1 = *(const uint4*)(Ap + step64);
  uint4 b0 = *(const uint4*)Bp;
  uint4 b1 = *(const uint4*)(Bp + step64);

  for (int kt = 0; kt < K; kt += 32) {
    __syncthreads();
    *(uint4*)&Al[sr * 40 + sk]        = a0;
    *(uint4*)&Al[(sr + 64) * 40 + sk] = a1;
    *(uint4*)&Bl[sr * 40 + sk]        = b0;
    *(uint4*)&Bl[(sr + 64) * 40 + sk] = b1;
    __syncthreads();
    if (kt + 32 < K) {
      a0 = *(const uint4*)(Ap + kt + 32);
      a1 = *(const uint4*)(Ap + step64 + kt + 32);
      b0 = *(const uint4*)(Bp + kt + 32);
      b1 = *(const uint4*)(Bp + step64 + kt + 32);
    }
    bf16x8 af[4], bf[4];
    #pragma unroll
    for (int mt = 0; mt < 4; mt++)
      af[mt] = *(const bf16x8*)&Al[(m0 + mt * 16 + l15) * 40 + l4 * 8];
    #pragma unroll
    for (int nt = 0; nt < 4; nt++)
      bf[nt] = *(const bf16x8*)&Bl[(n0 + nt * 16 + l15) * 40 + l4 * 8];
    #pragma unroll
    for (int mt = 0; mt < 4; mt++)
      #pragma unroll
      for (int nt = 0; nt < 4; nt++)
        acc[mt][nt] = __builtin_amdgcn_mfma_f32_16x16x32_bf16(af[mt], bf[nt], acc[mt][nt], 0, 0, 0);
  }

  #pragma unroll
  for (int nt = 0; nt < 4; nt++) {
    int col = col0 + n0 + nt * 16 + l15;
    float bb = ldin(bias, col, in_f32);
    #pragma unroll
    for (int mt = 0; mt < 4; mt++) {
      #pragma unroll
      for (int r = 0; r < 4; r++) {
        float v = (acc[mt][nt][r] + bb) * alpha;
        if (relu) v = fmaxf(v, 0.f);
        int row = row0 + m0 + mt * 16 + l4 * 4 + r;
        C[(size_t)row * N + col] = f2b(v);
      }
    }
  }
}

// ---------------------------------------------------------------------------
// MERGED KV2+QKV projection GEMM (one dispatch, grid (256,10)).
// by<4: A = x2 raw -> {k2 -> K2o, v2t -> V2to}.
// by>=4: A = x1 raw -> {k1 -> K1o, v1t -> V1to, q*qalpha -> Qo}.
// A dtype converted INLINE during staging (ldA8<F32>): no conv pass.
// Weights: S5 pack rows lby*128.. of [768][256] (k|v|q).
// ---------------------------------------------------------------------------
template<int F32>
__device__ __forceinline__ void kvqkv_body(
    const void* __restrict__ X2, const void* __restrict__ X1,
    const ushortT* __restrict__ Wt,
    const void* __restrict__ bk, const void* __restrict__ bv,
    const void* __restrict__ bq,
    ushortT* __restrict__ K2o, ushortT* __restrict__ V2to,
    ushortT* __restrict__ K1o, ushortT* __restrict__ V1to,
    ushortT* __restrict__ Qo, float qalpha,
    ushortT* Al, ushortT* Bl)
{
  const int tid = threadIdx.x;
  const int wave = tid >> 6, lane = tid & 63;
  const int l15 = lane & 15, l4 = lane >> 4;
  const int wm = wave & 1, wn = wave >> 1;

  // XCD swizzle: x-major over 2560 blocks (chunk 320/XCD -> 32 bx rows each)
  const int lin = blockIdx.x + 256 * blockIdx.y;
  const int gsw = (lin & 7) * 320 + (lin >> 3);
  const int bx = gsw / 10, by = gsw - bx * 10;
  const int row0 = bx * 128;
  const int grp = by >= 4;
  const int lby = grp ? by - 4 : by;
  const void* A = grp ? X1 : X2;
  const int brow0 = lby * 128;
  const int m0 = wm * 64, n0 = wn * 64;

  f32x4 acc[4][4];
  #pragma unroll
  for (int i = 0; i < 4; i++)
    #pragma unroll
    for (int j = 0; j < 4; j++) acc[i][j] = (f32x4)0.f;

  const int sr = tid >> 2;
  const int sk = (tid & 3) * 8;

  const size_t aBase = (size_t)(row0 + sr) * 256 + sk;
  const ushortT* Bp = &Wt[(size_t)(brow0 + sr) * 256 + sk];

  uint4 a0 = ldA8<F32>(A, aBase);
  uint4 a1 = ldA8<F32>(A, aBase + 64 * 256);
  uint4 b0 = *(const uint4*)Bp;
  uint4 b1 = *(const uint4*)(Bp + 64 * 256);

  for (int kt = 0; kt < 256; kt += 32) {
    __syncthreads();
    *(uint4*)&Al[sr * 40 + sk]        = a0;
    *(uint4*)&Al[(sr + 64) * 40 + sk] = a1;
    *(uint4*)&Bl[sr * 40 + sk]        = b0;
    *(uint4*)&Bl[(sr + 64) * 40 + sk] = b1;
    __syncthreads();
    if (kt + 32 < 256) {
      a0 = ldA8<F32>(A, aBase + kt + 32);
      a1 = ldA8<F32>(A, aBase + 64 * 256 + kt + 32);
      b0 = *(const uint4*)(Bp + kt + 32);
      b1 = *(const uint4*)(Bp + 64 * 256 + kt + 32);
    }
    bf16x8 af[4], bf[4];
    #pragma unroll
    for (int mt = 0; mt < 4; mt++)
      af[mt] = *(const bf16x8*)&Al[(m0 + mt * 16 + l15) * 40 + l4 * 8];
    #pragma unroll
    for (int nt = 0; nt < 4; nt++)
      bf[nt] = *(const bf16x8*)&Bl[(n0 + nt * 16 + l15) * 40 + l4 * 8];
    #pragma unroll
    for (int mt = 0; mt < 4; mt++)
      #pragma unroll
      for (int nt = 0; nt < 4; nt++)
        acc[mt][nt] = __builtin_amdgcn_mfma_f32_16x16x32_bf16(af[mt], bf[nt], acc[mt][nt], 0, 0, 0);
  }

  const int seg = lby >> 1;            // 0=k, 1=v(transposed), 2=q
  const int cb  = (lby & 1) * 128;

  if (seg == 1) {
    ushortT* Vt = grp ? V1to : V2to;
    const int bb  = row0 >> 8;
    const int tl0 = (row0 & 255) + m0 + l4 * 4;
    #pragma unroll
    for (int nt = 0; nt < 4; nt++) {
      const int col = cb + n0 + nt * 16 + l15;
      const float bbv = ldin(bv, col, F32);
      #pragma unroll
      for (int mt = 0; mt < 4; mt++) {
        ushort4 o;
        o.x = f2b(acc[mt][nt][0] + bbv);
        o.y = f2b(acc[mt][nt][1] + bbv);
        o.z = f2b(acc[mt][nt][2] + bbv);
        o.w = f2b(acc[mt][nt][3] + bbv);
        *(ushort4*)&Vt[(size_t)bb * 65536 + (size_t)col * 256 + tl0 + mt * 16] = o;
      }
    }
  } else {
    ushortT* C = (seg == 2) ? Qo : (grp ? K1o : K2o);
    const void* bp = (seg == 2) ? bq : bk;
    const float al = (seg == 2) ? qalpha : 1.f;
    #pragma unroll
    for (int nt = 0; nt < 4; nt++) {
      const int col = cb + n0 + nt * 16 + l15;
      const float bb = ldin(bp, col, F32);
      #pragma unroll
      for (int mt = 0; mt < 4; mt++) {
        #pragma unroll
        for (int r = 0; r < 4; r++) {
          const float v = (acc[mt][nt][r] + bb) * al;
          const int row = row0 + m0 + mt * 16 + l4 * 4 + r;
          C[(size_t)row * 256 + col] = f2b(v);
        }
      }
    }
  }
}

__global__ __launch_bounds__(256) void gemm_kvqkv_kernel(
    const void* __restrict__ X2, const void* __restrict__ X1,
    const ushortT* __restrict__ Wt,
    const void* __restrict__ bk, const void* __restrict__ bv,
    const void* __restrict__ bq,
    ushortT* __restrict__ K2o, ushortT* __restrict__ V2to,
    ushortT* __restrict__ K1o, ushortT* __restrict__ V1to,
    ushortT* __restrict__ Qo, float qalpha,
    const ushortT* __restrict__ sniffp)
{
  __shared__ ushortT Al[128 * 40];
  __shared__ ushortT Bl[128 * 40];
  const int in_f32 = sniff_wave(sniffp);
  if (in_f32)
    kvqkv_body<1>(X2, X1, Wt, bk, bv, bq, K2o, V2to, K1o, V1to, Qo, qalpha, Al, Bl);
  else
    kvqkv_body<0>(X2, X1, Wt, bk, bv, bq, K2o, V2to, K1o, V1to, Qo, qalpha, Al, Bl);
}

// ---------------------------------------------------------------------------
// Fused add + LayerNorm v2 (round-3 validated; unchanged).
// ---------------------------------------------------------------------------
#define LNROWS 4
__global__ __launch_bounds__(256) void add_ln_kernel(
    const void* __restrict__ X, const ushortT* __restrict__ Y,
    const void* __restrict__ gamma, const void* __restrict__ beta,
    void* __restrict__ out, const ushortT* __restrict__ sniffp,
    int x_dyn, int store_dyn)
{
  const int in_f32 = sniff_wave(sniffp);
  const int xf32 = x_dyn ? in_f32 : 0;
  const int lane = threadIdx.x & 63;
  const int gw = blockIdx.x * 4 + (threadIdx.x >> 6);
  const int d0 = lane * 4;

  float g[4], be[4];
  if (in_f32) {
    float4 gv = *(const float4*)((const float*)gamma + d0);
    float4 bv = *(const float4*)((const float*)beta  + d0);
    g[0]=gv.x; g[1]=gv.y; g[2]=gv.z; g[3]=gv.w;
    be[0]=bv.x; be[1]=bv.y; be[2]=bv.z; be[3]=bv.w;
  } else {
    ushort4 gv = *(const ushort4*)((const ushortT*)gamma + d0);
    ushort4 bv = *(const ushort4*)((const ushortT*)beta  + d0);
    g[0]=b2f(gv.x); g[1]=b2f(gv.y); g[2]=b2f(gv.z); g[3]=b2f(gv.w);
    be[0]=b2f(bv.x); be[1]=b2f(bv.y); be[2]=b2f(bv.z); be[3]=b2f(bv.w);
  }

  const int row0 = gw * LNROWS;

  float v[LNROWS][4];
  #pragma unroll
  for (int rr = 0; rr < LNROWS; rr++) {
    const size_t base = (size_t)(row0 + rr) * D_ + d0;
    const ushort4 yv = *(const ushort4*)(Y + base);
    if (xf32) {
      float4 xv = *(const float4*)((const float*)X + base);
      v[rr][0] = xv.x + b2f(yv.x); v[rr][1] = xv.y + b2f(yv.y);
      v[rr][2] = xv.z + b2f(yv.z); v[rr][3] = xv.w + b2f(yv.w);
    } else {
      ushort4 xv = *(const ushort4*)((const ushortT*)X + base);
      v[rr][0] = b2f(xv.x) + b2f(yv.x); v[rr][1] = b2f(xv.y) + b2f(yv.y);
      v[rr][2] = b2f(xv.z) + b2f(yv.z); v[rr][3] = b2f(xv.w) + b2f(yv.w);
    }
  }

  #pragma unroll
  for (int rr = 0; rr < LNROWS; rr++) {
    float s = (v[rr][0] + v[rr][1]) + (v[rr][2] + v[rr][3]);
    float q = (v[rr][0]*v[rr][0] + v[rr][1]*v[rr][1])
            + (v[rr][2]*v[rr][2] + v[rr][3]*v[rr][3]);
    #pragma unroll
    for (int off = 1; off < 64; off <<= 1) {
      s += __shfl_xor(s, off, 64);
      q += __shfl_xor(q, off, 64);
    }
    const float mu   = s * (1.f / D_);
    const float var  = q * (1.f / D_) - mu * mu;
    const float rstd = rsqrtf(var + 1e-6f);
    const size_t base = (size_t)(row0 + rr) * D_ + d0;
    if (store_dyn && in_f32) {
      float4 o;
      o.x = g[0]*(v[rr][0]-mu)*rstd + be[0];
      o.y = g[1]*(v[rr][1]-mu)*rstd + be[1];
      o.z = g[2]*(v[rr][2]-mu)*rstd + be[2];
      o.w = g[3]*(v[rr][3]-mu)*rstd + be[3];
      *(float4*)((float*)out + base) = o;
    } else {
      ushort4 o;
      o.x = f2b(g[0]*(v[rr][0]-mu)*rstd + be[0]);
      o.y = f2b(g[1]*(v[rr][1]-mu)*rstd + be[1]);
      o.z = f2b(g[2]*(v[rr][2]-mu)*rstd + be[2]);
      o.w = f2b(g[3]*(v[rr][3]-mu)*rstd + be[3]);
      *(ushort4*)((ushortT*)out + base) = o;
    }
  }
}

// ---------------------------------------------------------------------------
// MFMA dual attention (round-10 variant; measured plateau ~125 us; unchanged).
// ---------------------------------------------------------------------------
__global__ __launch_bounds__(256, 4) void attn_mfma_kernel(
    ushortT* __restrict__ QC,
    const ushortT* __restrict__ K1, const ushortT* __restrict__ K2,
    const ushortT* __restrict__ V1t, const ushortT* __restrict__ V2t,
    const uintT* __restrict__ AB, const uintT* __restrict__ MW)
{
  const int lin = blockIdx.x + (blockIdx.y << 2) + (blockIdx.z << 5);
  const int gsw = (lin & 7) * 512 + (lin >> 3);
  const int b = gsw >> 5, h = (gsw >> 2) & 7, qt = gsw & 3;
  const int q0 = qt * 64;
  const int tid = threadIdx.x;
  const int wave = tid >> 6, lane = tid & 63;
  const int l15 = lane & 15, l4 = lane >> 4;

  __shared__ __align__(16) ushortT P[64][256];   // 32 KiB, XOR-swizzled rows

  const size_t bh = (size_t)b * 256;
  const int prow = wave * 16 + l15;
  const uintT swz = (uintT)((prow & 7) << 4);
  char* Prow = (char*)&P[prow][0];

  uintT adjr[8];
  {
    const uintT* abp = AB + ((size_t)(b * 256 + q0 + prow)) * 8;
    const uint4 a0 = *(const uint4*)abp;
    const uint4 a1 = *(const uint4*)(abp + 4);
    adjr[0]=a0.x; adjr[1]=a0.y; adjr[2]=a0.z; adjr[3]=a0.w;
    adjr[4]=a1.x; adjr[5]=a1.y; adjr[6]=a1.z; adjr[7]=a1.w;
  }

  const bf16x8 af = *(const bf16x8*)&QC[(bh + q0 + wave*16 + l15) * 256 + h*32 + l4*8];

  f32x4 acc0 = (f32x4)0.f, acc1 = (f32x4)0.f;

  #pragma unroll 1
  for (int src = 0; src < 2; src++) {
    const ushortT* Kp  = src ? K2  : K1;
    const ushortT* Vtp = src ? V2t : V1t;

    const uintT* mwp = MW + (src * 128 + b) * 8;
    uintT mww[8];
    #pragma unroll
    for (int w = 0; w < 8; w++) mww[w] = mwp[w];

    float rsum = 0.f;
    #pragma unroll
    for (int c = 0; c < 4; c++) {
      bf16x8 kf[4];
      #pragma unroll
      for (int j = 0; j < 4; j++)
        kf[j] = *(const bf16x8*)&Kp[(bh + (c*4 + j)*16 + l15) * 256 + h*32 + l4*8];
      #pragma unroll
      for (int j = 0; j < 4; j++) {
        const int nt = c*4 + j;
        const f32x4 s4 = __builtin_amdgcn_mfma_f32_16x16x32_bf16(kf[j], af, (f32x4)0.f, 0, 0, 0);
        const int tb = nt*16 + l4*4;
        const int sh = tb & 31;
        uintT bits = mww[nt >> 1] >> sh;
        if (src == 0) bits &= adjr[nt >> 1] >> sh;
        const float e0 = (bits & 1u) ? EXP2(s4[0]) : 0.f;
        const float e1 = (bits & 2u) ? EXP2(s4[1]) : 0.f;
        const float e2 = (bits & 4u) ? EXP2(s4[2]) : 0.f;
        const float e3 = (bits & 8u) ? EXP2(s4[3]) : 0.f;
        rsum += (e0 + e1) + (e2 + e3);
        uintT pk01, pk23;
        asm("v_cvt_pk_bf16_f32 %0, %1, %2" : "=v"(pk01) : "v"(e0), "v"(e1));
        asm("v_cvt_pk_bf16_f32 %0, %1, %2" : "=v"(pk23) : "v"(e2), "v"(e3));
        uint2 pw; pw.x = pk01; pw.y = pk23;
        *(uint2*)(Prow + (((uintT)(tb*2)) ^ swz)) = pw;
      }
    }
    rsum += __shfl_xor(rsum, 16, 64);
    rsum += __shfl_xor(rsum, 32, 64);
    const float rv = 1.f / rsum;
    float rvr[4];
    #pragma unroll
    for (int r = 0; r < 4; r++) rvr[r] = __shfl(rv, l4*4 + r, 64);

    f32x4 o0 = (f32x4)0.f, o1 = (f32x4)0.f;
    __builtin_amdgcn_s_setprio(1);
    #pragma unroll
    for (int kt = 0; kt < 8; kt++) {
      const bf16x8 ap = *(const bf16x8*)(Prow + (((uintT)(kt*64 + l4*16)) ^ swz));
      const bf16x8 v0 = *(const bf16x8*)&Vtp[(bh + h*32 + l15) * 256 + kt*32 + l4*8];
      const bf16x8 v1 = *(const bf16x8*)&Vtp[(bh + h*32 + 16 + l15) * 256 + kt*32 + l4*8];
      o0 = __builtin_amdgcn_mfma_f32_16x16x32_bf16(ap, v0, o0, 0, 0, 0);
      o1 = __builtin_amdgcn_mfma_f32_16x16x32_bf16(ap, v1, o1, 0, 0, 0);
    }
    __builtin_amdgcn_s_setprio(0);
    #pragma unroll
    for (int r = 0; r < 4; r++) { acc0[r] += o0[r] * rvr[r]; acc1[r] += o1[r] * rvr[r]; }
  }

  #pragma unroll
  for (int r = 0; r < 4; r++) {
    const int row = (int)(bh + q0 + wave*16 + l4*4 + r);
    QC[(size_t)row * 256 + h*32 + l15]      = f2b(acc0[r]);
    QC[(size_t)row * 256 + h*32 + 16 + l15] = f2b(acc1[r]);
  }
}

// ---------------------------------------------------------------------------
// Orchestration v6: 8 dispatches.
//  1. prep (pack adj+masks, Wk|Wv|Wq|Wo -> S5, W1t, W2t)      [1 dispatch]
//  2. kvqkv merged: x2 -> {k2@S3, v2t@S1}, x1 -> {k1@S2, v1t@S4, q@qbuf}
//     (A dtype converted inline; no conv pass)                [1 dispatch]
//  3. attn: q@qbuf -> c@qbuf
//  4. proj: c@qbuf x Wot@S5 -> S3
//  5. LN1: x1 + S3 -> S0
//  6. FFN1: S0 x W1t -> S1   7. FFN2: S1 x W2t -> S5 (pack dead)
//  8. LN2: S0 + S5 -> d_out
// ---------------------------------------------------------------------------
extern "C" void kernel_launch(void* const* d_in, const int* in_sizes, int n_in,
                              void* d_out, int out_size, void* d_ws, size_t ws_size,
                              hipStream_t stream) {
  const void* x1    = d_in[0];
  const void* adj1  = d_in[1];
  const void* mask1 = d_in[2];
  const void* x2    = d_in[3];
  const void* mask2 = d_in[4];
  const void* Wq = d_in[5];  const void* bq = d_in[6];
  const void* Wk = d_in[7];  const void* bk = d_in[8];
  const void* Wv = d_in[9];  const void* bv = d_in[10];
  const void* Wo = d_in[11]; const void* bo = d_in[12];
  const void* W1 = d_in[13]; const void* b1 = d_in[14];
  const void* W2 = d_in[15]; const void* b2 = d_in[16];
  const void* g1 = d_in[17]; const void* be1= d_in[18];
  const void* g2 = d_in[19]; const void* be2= d_in[20];
  const ushortT* sniffp = (const ushortT*)x1;

  ushortT* ws = (ushortT*)d_ws;
  const size_t SZ = (size_t)M_ * D_;
  ushortT* S0 = ws;
  ushortT* S1 = ws + SZ;
  ushortT* S2 = ws + 2*SZ;
  ushortT* S3 = ws + 3*SZ;
  ushortT* S4 = ws + 4*SZ;
  ushortT* S5 = ws + 5*SZ;
  ushortT* dOut = (ushortT*)d_out;

  ushortT* Wpack = S5;               // [1024][256]: k|v|q|o
  ushortT* Wot   = S5 + 196608;
  ushortT* W1t = dOut;               // [1024][256] @ dOut 0..512K elems
  ushortT* W2t = dOut + 262144;      // [256][1024] @ 512K..1M elems
  ushortT* qbuf = dOut + 524288;     // q/c scratch (1..17.8 MB)
  uintT* AB = (uintT*)(dOut + 9437184);   // 1 MiB @ +18.9 MB
  uintT* MWp = AB + 262144;               // 2048 words

  const float qalpha = 0.25503486f;  // 1/sqrt(32) * log2(e)

  dim3 blk(256);
  dim3 gGemmD(M_/128, D_/128);       // (256, 2)
  dim3 gGemmF(M_/128, DFF_/128);     // (256, 8)
  dim3 gKVQKV(256, 10);              // merged projections

  // 1) prep: all packs + weight transposes
  prep_kernel<<<dim3(1800), blk, 0, stream>>>(
      adj1, AB, mask1, mask2, MWp, Wk, Wv, Wq, Wo, Wpack, W1, W1t, W2, W2t, sniffp);

  // 2) merged projections (inline dtype conversion of x1/x2)
  gemm_kvqkv_kernel<<<gKVQKV, blk, 0, stream>>>(
      x2, x1, Wpack, bk, bv, bq, S3, S1, S2, S4, qbuf, qalpha, sniffp);

  // 3) attention: q@qbuf -> c@qbuf ; k1@S2 k2@S3 v1t@S4 v2t@S1
  attn_mfma_kernel<<<dim3(N1_/64, H_, B_), blk, 0, stream>>>(
      qbuf, S2, S3, S4, S1, AB, MWp);

  // 4) proj: c@qbuf x Wot@S5 -> S3
  gemm128_kernel<<<gGemmD, blk, 0, stream>>>(qbuf, Wot, bo, S3, M_, D_, D_, 0, 1.f, sniffp);

  // 5) LN1: x1 + attnp@S3 -> out1@S0
  add_ln_kernel<<<dim3(M_/16), blk, 0, stream>>>(x1, S3, g1, be1, S0, sniffp, 1, 0);

  // 6) FFN1: relu(out1@S0 x W1t^T + b1) -> S1..S4
  gemm128_kernel<<<gGemmF, blk, 0, stream>>>(S0, W1t, b1, S1, M_, DFF_, D_, 1, 1.f, sniffp);

  // 7) FFN2: ffn1@S1 x W2t^T + b2 -> S5
  gemm128_kernel<<<gGemmD, blk, 0, stream>>>(S1, W2t, b2, S5, M_, D_, DFF_, 0, 1.f, sniffp);

  // 8) LN2: out1@S0 + ffn2@S5 -> d_out (f32 fresh write)
  add_ln_kernel<<<dim3(M_/16), blk, 0, stream>>>(S0, S5, g2, be2, d_out, sniffp, 0, 1);
}

// Round 16
// 439.202 us; speedup vs baseline: 1.0309x; 1.0309x over previous
//
#include <hip/hip_runtime.h>
#include <hip/hip_bf16.h>
#include <stdint.h>

// Problem constants (PrismEncoder)
#define B_   128
#define N1_  256
#define N2_  256
#define D_   256
#define H_   8
#define DH_  32
#define DFF_ 1024
#define M_   (B_*N1_)   // 32768 rows

typedef unsigned short ushortT;
typedef unsigned int   uintT;
typedef short bf16x8 __attribute__((ext_vector_type(8)));
typedef float f32x4  __attribute__((ext_vector_type(4)));

#if __has_builtin(__builtin_amdgcn_exp2f)
#define EXP2(x) __builtin_amdgcn_exp2f(x)
#else
#define EXP2(x) exp2f(x)
#endif

__device__ __forceinline__ float b2f(ushortT u){ return __uint_as_float(((uintT)u)<<16); }
__device__ __forceinline__ ushortT f2b(float f){
  uintT u = __float_as_uint(f);
  uintT r = (u + 0x7fffu + ((u>>16)&1u)) >> 16;   // RNE
  return (ushortT)r;
}

// Dtype sniff, wave-parallel.
__device__ __forceinline__ int sniff_wave(const ushortT* x){
  const int e = (x[threadIdx.x & 63] >> 7) & 0xff;
  const unsigned long long bad = __ballot(e < 100 || e > 135);
  return __popcll(bad) >= 12;
}
__device__ __forceinline__ float ldin(const void* p, size_t i, int f32){
  return f32 ? ((const float*)p)[i] : b2f(((const ushortT*)p)[i]);
}

// ---------------------------------------------------------------------------
// Convert BOTH input tensors (x1 -> Y1, x2 -> Y2) in one dispatch.
// (r15 lesson: separate conv pass beats inline-f32 GEMM staging — the GEMM
// re-reads A per column-block, so A must be bf16.)
// ---------------------------------------------------------------------------
__global__ __launch_bounds__(256) void conv2_bf16_kernel(
    const void* __restrict__ X1, ushortT* __restrict__ Y1,
    const void* __restrict__ X2, ushortT* __restrict__ Y2,
    int nblk1, const ushortT* __restrict__ sniffp)
{
  const int in_f32 = sniff_wave(sniffp);
  const int second = blockIdx.x >= nblk1;
  const void* X = second ? X2 : X1;
  ushortT* Y = second ? Y2 : Y1;
  const int i = (second ? blockIdx.x - nblk1 : blockIdx.x) * 256 + threadIdx.x;
  const size_t base = (size_t)i * 8;
  if (in_f32) {
    float4 a = *(const float4*)((const float*)X + base);
    float4 b = *(const float4*)((const float*)X + base + 4);
    ushort4 o0, o1;
    o0.x=f2b(a.x); o0.y=f2b(a.y); o0.z=f2b(a.z); o0.w=f2b(a.w);
    o1.x=f2b(b.x); o1.y=f2b(b.y); o1.z=f2b(b.z); o1.w=f2b(b.w);
    *(ushort4*)(Y + base)     = o0;
    *(ushort4*)(Y + base + 4) = o1;
  } else {
    *(uint4*)(Y + base) = *(const uint4*)((const ushortT*)X + base);
  }
}

// ---------------------------------------------------------------------------
// 32x32 transpose tile body (barrier is uniform per-block: callers branch
// on blockIdx only).
// ---------------------------------------------------------------------------
__device__ __forceinline__ void tw_body(
    const void* W, ushortT* Wt, int K, int N, int xb, int yb, int in_f32,
    float (*t)[33])
{
  const int tx = threadIdx.x & 31, ty = threadIdx.x >> 5;  // ty 0..7
  const int n0 = xb * 32, k0 = yb * 32;
  #pragma unroll
  for (int i = 0; i < 4; i++)
    t[ty + 8*i][tx] = ldin(W, (size_t)(k0 + ty + 8*i) * N + n0 + tx, in_f32);
  __syncthreads();
  #pragma unroll
  for (int i = 0; i < 4; i++)
    Wt[(size_t)(n0 + ty + 8*i) * K + k0 + tx] = f2b(t[tx][ty + 8*i]);
}

// ---------------------------------------------------------------------------
// PREP (single dispatch, 1800 blocks): adjacency+mask bit-pack, Wk|Wv|Wq|Wo
// -> S5 pack, W1t, W2t. All independent (r15-validated; perf-neutral merge).
//   [0,1024)    adj pack    [1024,1032) mask pack
//   [1032,1288) w4 256x256  [1288,1544) W1t (32x8)  [1544,1800) W2t (8x32)
// ---------------------------------------------------------------------------
__global__ __launch_bounds__(256) void prep_kernel(
    const void* __restrict__ ADJ, uintT* __restrict__ AB,
    const void* __restrict__ M1, const void* __restrict__ M2,
    uintT* __restrict__ MW,
    const void* __restrict__ Wk, const void* __restrict__ Wv,
    const void* __restrict__ Wq, const void* __restrict__ Wo,
    ushortT* __restrict__ Wpack,
    const void* __restrict__ W1, ushortT* __restrict__ W1t,
    const void* __restrict__ W2, ushortT* __restrict__ W2t,
    const ushortT* __restrict__ sniffp)
{
  __shared__ float t[32][33];
  const int in_f32 = sniff_wave(sniffp);
  const int bid = blockIdx.x;

  if (bid < 1024) {
    const int idx = bid * 256 + threadIdx.x;               // 262144 words
    const size_t base = (size_t)(idx >> 3) * 256 + (size_t)(idx & 7) * 32;
    uintT bits = 0;
    if (in_f32) {
      const float* ap = (const float*)ADJ + base;
      #pragma unroll
      for (int j4 = 0; j4 < 8; j4++) {
        float4 v = *(const float4*)(ap + j4 * 4);
        bits |= (v.x > 0.f ? 1u : 0u) << (j4 * 4 + 0);
        bits |= (v.y > 0.f ? 1u : 0u) << (j4 * 4 + 1);
        bits |= (v.z > 0.f ? 1u : 0u) << (j4 * 4 + 2);
        bits |= (v.w > 0.f ? 1u : 0u) << (j4 * 4 + 3);
      }
    } else {
      const ushortT* ap = (const ushortT*)ADJ + base;
      #pragma unroll
      for (int j = 0; j < 32; j++)
        bits |= (b2f(ap[j]) > 0.f ? 1u : 0u) << j;
    }
    AB[idx] = bits;
    return;
  }
  if (bid < 1032) {
    const int idx = (bid - 1024) * 256 + threadIdx.x;      // 2048 words
    const int src = idx >> 10;
    const void* MP = src ? M2 : M1;
    const size_t base = (size_t)((idx >> 3) & 127) * 256 + (size_t)(idx & 7) * 32;
    uintT bits = 0;
    #pragma unroll
    for (int j = 0; j < 32; j++)
      bits |= (ldin(MP, base + j, in_f32) > 0.f ? 1u : 0u) << j;
    MW[idx] = bits;
    return;
  }
  if (bid < 1288) {
    const int idx = bid - 1032;                            // 256: 8x8x4
    const int z = idx >> 6, yb = (idx >> 3) & 7, xb = idx & 7;
    const void* W = (z == 0) ? Wk : (z == 1) ? Wv : (z == 2) ? Wq : Wo;
    tw_body(W, Wpack + (size_t)z * 65536, 256, 256, xb, yb, in_f32, t);
    return;
  }
  if (bid < 1544) {
    const int idx = bid - 1288;                            // 256: 32x8
    tw_body(W1, W1t, 256, 1024, idx & 31, idx >> 5, in_f32, t);
    return;
  }
  {
    const int idx = bid - 1544;                            // 256: 8x32
    tw_body(W2, W2t, 1024, 256, idx & 7, idx >> 3, in_f32, t);
  }
}

// ---------------------------------------------------------------------------
// MFMA GEMM v5 (proven best): 128x128 tile, 2x2 waves, 4x4 16x16x32 frags,
// BK=32, LDS stride 40 (2-way free), VGPR prefetch, XCD swizzle (pow2 gy).
// C = (A[M,K] @ Bt[N,K]^T + bias) * alpha, relu.
// ---------------------------------------------------------------------------
__global__ __launch_bounds__(256) void gemm128_kernel(
    const ushortT* __restrict__ A, const ushortT* __restrict__ Bt,
    const void* __restrict__ bias, ushortT* __restrict__ C,
    int M, int N, int K, int relu, float alpha,
    const ushortT* __restrict__ sniffp)
{
  __shared__ ushortT Al[128 * 40];
  __shared__ ushortT Bl[128 * 40];

  const int tid = threadIdx.x;
  const int in_f32 = sniff_wave(sniffp);
  const int wave = tid >> 6, lane = tid & 63;
  const int l15 = lane & 15, l4 = lane >> 4;
  const int wm = wave & 1, wn = wave >> 1;

  const int lin = blockIdx.x + gridDim.x * blockIdx.y;
  const int chunk = (gridDim.x * gridDim.y) >> 3;
  const int gsw = (lin & 7) * chunk + (lin >> 3);
  const int ylog = 31 - __clz(gridDim.y);
  const int bx = gsw >> ylog, by = gsw & (gridDim.y - 1);
  const int row0 = bx * 128, col0 = by * 128;
  const int m0 = wm * 64, n0 = wn * 64;

  f32x4 acc[4][4];
  #pragma unroll
  for (int i = 0; i < 4; i++)
    #pragma unroll
    for (int j = 0; j < 4; j++) acc[i][j] = (f32x4)0.f;

  const int sr = tid >> 2;          // 0..63
  const int sk = (tid & 3) * 8;     // 0,8,16,24

  const ushortT* Ap = &A[(size_t)(row0 + sr) * K + sk];
  const ushortT* Bp = &Bt[(size_t)(col0 + sr) * K + sk];
  const size_t step64 = (size_t)64 * K;

  uint4 a0 = *(const uint4*)Ap;
  uint4 a1 = *(const uint4*)(Ap + step64);
  uint4 b0 = *(const uint4*)Bp;
  uint4 b1 = *(const uint4*)(Bp + step64);

  for (int kt = 0; kt < K; kt += 32) {
    __syncthreads();
    *(uint4*)&Al[sr * 40 + sk]        = a0;
    *(uint4*)&Al[(sr + 64) * 40 + sk] = a1;
    *(uint4*)&Bl[sr * 40 + sk]        = b0;
    *(uint4*)&Bl[(sr + 64) * 40 + sk] = b1;
    __syncthreads();
    if (kt + 32 < K) {
      a0 = *(const uint4*)(Ap + kt + 32);
      a1 = *(const uint4*)(Ap + step64 + kt + 32);
      b0 = *(const uint4*)(Bp + kt + 32);
      b1 = *(const uint4*)(Bp + step64 + kt + 32);
    }
    bf16x8 af[4], bf[4];
    #pragma unroll
    for (int mt = 0; mt < 4; mt++)
      af[mt] = *(const bf16x8*)&Al[(m0 + mt * 16 + l15) * 40 + l4 * 8];
    #pragma unroll
    for (int nt = 0; nt < 4; nt++)
      bf[nt] = *(const bf16x8*)&Bl[(n0 + nt * 16 + l15) * 40 + l4 * 8];
    #pragma unroll
    for (int mt = 0; mt < 4; mt++)
      #pragma unroll
      for (int nt = 0; nt < 4; nt++)
        acc[mt][nt] = __builtin_amdgcn_mfma_f32_16x16x32_bf16(af[mt], bf[nt], acc[mt][nt], 0, 0, 0);
  }

  #pragma unroll
  for (int nt = 0; nt < 4; nt++) {
    int col = col0 + n0 + nt * 16 + l15;
    float bb = ldin(bias, col, in_f32);
    #pragma unroll
    for (int mt = 0; mt < 4; mt++) {
      #pragma unroll
      for (int r = 0; r < 4; r++) {
        float v = (acc[mt][nt][r] + bb) * alpha;
        if (relu) v = fmaxf(v, 0.f);
        int row = row0 + m0 + mt * 16 + l4 * 4 + r;
        C[(size_t)row * N + col] = f2b(v);
      }
    }
  }
}

// ---------------------------------------------------------------------------
// Fused multi-head GEMM (r12/r14 validated, reg-staged, bf16 A).
// Segment = col0>>8: 0 -> C0 normal (b0), 1 -> C1 direct-transposed
// Vt[b][d][t] (b1), 2 -> C2 * alpha2 (b2).
// ---------------------------------------------------------------------------
__global__ __launch_bounds__(256) void gemm_qkv_kernel(
    const ushortT* __restrict__ A, const ushortT* __restrict__ Bt,
    const void* __restrict__ b0p, const void* __restrict__ b1p,
    const void* __restrict__ b2p,
    ushortT* __restrict__ C0, ushortT* __restrict__ C1,
    ushortT* __restrict__ C2,
    int K, float alpha2, const ushortT* __restrict__ sniffp)
{
  __shared__ ushortT Al[128 * 40];
  __shared__ ushortT Bl[128 * 40];

  const int tid = threadIdx.x;
  const int in_f32 = sniff_wave(sniffp);
  const int wave = tid >> 6, lane = tid & 63;
  const int l15 = lane & 15, l4 = lane >> 4;
  const int wm = wave & 1, wn = wave >> 1;

  // XCD swizzle, x-major (gy = 4 or 6, not pow2 -> div/mod decode)
  const int gy = gridDim.y;
  const int lin = blockIdx.x + gridDim.x * blockIdx.y;
  const int chunk = (gridDim.x * gy) >> 3;
  const int gsw = (lin & 7) * chunk + (lin >> 3);
  const int bx = gsw / gy, by = gsw - bx * gy;
  const int row0 = bx * 128, col0 = by * 128;
  const int m0 = wm * 64, n0 = wn * 64;

  f32x4 acc[4][4];
  #pragma unroll
  for (int i = 0; i < 4; i++)
    #pragma unroll
    for (int j = 0; j < 4; j++) acc[i][j] = (f32x4)0.f;

  const int sr = tid >> 2;
  const int sk = (tid & 3) * 8;

  const ushortT* Ap = &A[(size_t)(row0 + sr) * K + sk];
  const ushortT* Bp = &Bt[(size_t)(col0 + sr) * K + sk];
  const size_t step64 = (size_t)64 * K;

  uint4 a0 = *(const uint4*)Ap;
  uint4 a1 = *(const uint4*)(Ap + step64);
  uint4 b0 = *(const uint4*)Bp;
  uint4 b1 = *(const uint4*)(Bp + step64);

  for (int kt = 0; kt < K; kt += 32) {
    __syncthreads();
    *(uint4*)&Al[sr * 40 + sk]        = a0;
    *(uint4*)&Al[(sr + 64) * 40 + sk] = a1;
    *(uint4*)&Bl[sr * 40 + sk]        = b0;
    *(uint4*)&Bl[(sr + 64) * 40 + sk] = b1;
    __syncthreads();
    if (kt + 32 < K) {
      a0 = *(const uint4*)(Ap + kt + 32);
      a1 = *(const uint4*)(Ap + step64 + kt + 32);
      b0 = *(const uint4*)(Bp + kt + 32);
      b1 = *(const uint4*)(Bp + step64 + kt + 32);
    }
    bf16x8 af[4], bf[4];
    #pragma unroll
    for (int mt = 0; mt < 4; mt++)
      af[mt] = *(const bf16x8*)&Al[(m0 + mt * 16 + l15) * 40 + l4 * 8];
    #pragma unroll
    for (int nt = 0; nt < 4; nt++)
      bf[nt] = *(const bf16x8*)&Bl[(n0 + nt * 16 + l15) * 40 + l4 * 8];
    #pragma unroll
    for (int mt = 0; mt < 4; mt++)
      #pragma unroll
      for (int nt = 0; nt < 4; nt++)
        acc[mt][nt] = __builtin_amdgcn_mfma_f32_16x16x32_bf16(af[mt], bf[nt], acc[mt][nt], 0, 0, 0);
  }

  const int seg = col0 >> 8;         // 0=k, 1=v(transposed), 2=q(alpha)
  const int cb  = col0 & 255;

  if (seg == 1) {
    const int bb  = row0 >> 8;
    const int tl0 = (row0 & 255) + m0 + l4 * 4;
    #pragma unroll
    for (int nt = 0; nt < 4; nt++) {
      const int col = cb + n0 + nt * 16 + l15;
      const float bbv = ldin(b1p, col, in_f32);
      #pragma unroll
      for (int mt = 0; mt < 4; mt++) {
        ushort4 o;
        o.x = f2b(acc[mt][nt][0] + bbv);
        o.y = f2b(acc[mt][nt][1] + bbv);
        o.z = f2b(acc[mt][nt][2] + bbv);
        o.w = f2b(acc[mt][nt][3] + bbv);
        *(ushort4*)&C1[(size_t)bb * 65536 + (size_t)col * 256 + tl0 + mt * 16] = o;
      }
    }
  } else {
    ushortT* C = seg ? C2 : C0;
    const void* bp = seg ? b2p : b0p;
    const float al = seg ? alpha2 : 1.f;
    #pragma unroll
    for (int nt = 0; nt < 4; nt++) {
      const int col = cb + n0 + nt * 16 + l15;
      const float bb = ldin(bp, col, in_f32);
      #pragma unroll
      for (int mt = 0; mt < 4; mt++) {
        #pragma unroll
        for (int r = 0; r < 4; r++) {
          const float v = (acc[mt][nt][r] + bb) * al;
          const int row = row0 + m0 + mt * 16 + l4 * 4 + r;
          C[(size_t)row * 256 + col] = f2b(v);
        }
      }
    }
  }
}

// ---------------------------------------------------------------------------
// Fused add + LayerNorm v2 (round-3 validated; unchanged).
// ---------------------------------------------------------------------------
#define LNROWS 4
__global__ __launch_bounds__(256) void add_ln_kernel(
    const void* __restrict__ X, const ushortT* __restrict__ Y,
    const void* __restrict__ gamma, const void* __restrict__ beta,
    void* __restrict__ out, const ushortT* __restrict__ sniffp,
    int x_dyn, int store_dyn)
{
  const int in_f32 = sniff_wave(sniffp);
  const int xf32 = x_dyn ? in_f32 : 0;
  const int lane = threadIdx.x & 63;
  const int gw = blockIdx.x * 4 + (threadIdx.x >> 6);
  const int d0 = lane * 4;

  float g[4], be[4];
  if (in_f32) {
    float4 gv = *(const float4*)((const float*)gamma + d0);
    float4 bv = *(const float4*)((const float*)beta  + d0);
    g[0]=gv.x; g[1]=gv.y; g[2]=gv.z; g[3]=gv.w;
    be[0]=bv.x; be[1]=bv.y; be[2]=bv.z; be[3]=bv.w;
  } else {
    ushort4 gv = *(const ushort4*)((const ushortT*)gamma + d0);
    ushort4 bv = *(const ushort4*)((const ushortT*)beta  + d0);
    g[0]=b2f(gv.x); g[1]=b2f(gv.y); g[2]=b2f(gv.z); g[3]=b2f(gv.w);
    be[0]=b2f(bv.x); be[1]=b2f(bv.y); be[2]=b2f(bv.z); be[3]=b2f(bv.w);
  }

  const int row0 = gw * LNROWS;

  float v[LNROWS][4];
  #pragma unroll
  for (int rr = 0; rr < LNROWS; rr++) {
    const size_t base = (size_t)(row0 + rr) * D_ + d0;
    const ushort4 yv = *(const ushort4*)(Y + base);
    if (xf32) {
      float4 xv = *(const float4*)((const float*)X + base);
      v[rr][0] = xv.x + b2f(yv.x); v[rr][1] = xv.y + b2f(yv.y);
      v[rr][2] = xv.z + b2f(yv.z); v[rr][3] = xv.w + b2f(yv.w);
    } else {
      ushort4 xv = *(const ushort4*)((const ushortT*)X + base);
      v[rr][0] = b2f(xv.x) + b2f(yv.x); v[rr][1] = b2f(xv.y) + b2f(yv.y);
      v[rr][2] = b2f(xv.z) + b2f(yv.z); v[rr][3] = b2f(xv.w) + b2f(yv.w);
    }
  }

  #pragma unroll
  for (int rr = 0; rr < LNROWS; rr++) {
    float s = (v[rr][0] + v[rr][1]) + (v[rr][2] + v[rr][3]);
    float q = (v[rr][0]*v[rr][0] + v[rr][1]*v[rr][1])
            + (v[rr][2]*v[rr][2] + v[rr][3]*v[rr][3]);
    #pragma unroll
    for (int off = 1; off < 64; off <<= 1) {
      s += __shfl_xor(s, off, 64);
      q += __shfl_xor(q, off, 64);
    }
    const float mu   = s * (1.f / D_);
    const float var  = q * (1.f / D_) - mu * mu;
    const float rstd = rsqrtf(var + 1e-6f);
    const size_t base = (size_t)(row0 + rr) * D_ + d0;
    if (store_dyn && in_f32) {
      float4 o;
      o.x = g[0]*(v[rr][0]-mu)*rstd + be[0];
      o.y = g[1]*(v[rr][1]-mu)*rstd + be[1];
      o.z = g[2]*(v[rr][2]-mu)*rstd + be[2];
      o.w = g[3]*(v[rr][3]-mu)*rstd + be[3];
      *(float4*)((float*)out + base) = o;
    } else {
      ushort4 o;
      o.x = f2b(g[0]*(v[rr][0]-mu)*rstd + be[0]);
      o.y = f2b(g[1]*(v[rr][1]-mu)*rstd + be[1]);
      o.z = f2b(g[2]*(v[rr][2]-mu)*rstd + be[2]);
      o.w = f2b(g[3]*(v[rr][3]-mu)*rstd + be[3]);
      *(ushort4*)((ushortT*)out + base) = o;
    }
  }
}

// ---------------------------------------------------------------------------
// MFMA dual attention (round-10 variant; measured plateau ~125 us; unchanged).
// ---------------------------------------------------------------------------
__global__ __launch_bounds__(256, 4) void attn_mfma_kernel(
    ushortT* __restrict__ QC,
    const ushortT* __restrict__ K1, const ushortT* __restrict__ K2,
    const ushortT* __restrict__ V1t, const ushortT* __restrict__ V2t,
    const uintT* __restrict__ AB, const uintT* __restrict__ MW)
{
  const int lin = blockIdx.x + (blockIdx.y << 2) + (blockIdx.z << 5);
  const int gsw = (lin & 7) * 512 + (lin >> 3);
  const int b = gsw >> 5, h = (gsw >> 2) & 7, qt = gsw & 3;
  const int q0 = qt * 64;
  const int tid = threadIdx.x;
  const int wave = tid >> 6, lane = tid & 63;
  const int l15 = lane & 15, l4 = lane >> 4;

  __shared__ __align__(16) ushortT P[64][256];   // 32 KiB, XOR-swizzled rows

  const size_t bh = (size_t)b * 256;
  const int prow = wave * 16 + l15;
  const uintT swz = (uintT)((prow & 7) << 4);
  char* Prow = (char*)&P[prow][0];

  uintT adjr[8];
  {
    const uintT* abp = AB + ((size_t)(b * 256 + q0 + prow)) * 8;
    const uint4 a0 = *(const uint4*)abp;
    const uint4 a1 = *(const uint4*)(abp + 4);
    adjr[0]=a0.x; adjr[1]=a0.y; adjr[2]=a0.z; adjr[3]=a0.w;
    adjr[4]=a1.x; adjr[5]=a1.y; adjr[6]=a1.z; adjr[7]=a1.w;
  }

  const bf16x8 af = *(const bf16x8*)&QC[(bh + q0 + wave*16 + l15) * 256 + h*32 + l4*8];

  f32x4 acc0 = (f32x4)0.f, acc1 = (f32x4)0.f;

  #pragma unroll 1
  for (int src = 0; src < 2; src++) {
    const ushortT* Kp  = src ? K2  : K1;
    const ushortT* Vtp = src ? V2t : V1t;

    const uintT* mwp = MW + (src * 128 + b) * 8;
    uintT mww[8];
    #pragma unroll
    for (int w = 0; w < 8; w++) mww[w] = mwp[w];

    float rsum = 0.f;
    #pragma unroll
    for (int c = 0; c < 4; c++) {
      bf16x8 kf[4];
      #pragma unroll
      for (int j = 0; j < 4; j++)
        kf[j] = *(const bf16x8*)&Kp[(bh + (c*4 + j)*16 + l15) * 256 + h*32 + l4*8];
      #pragma unroll
      for (int j = 0; j < 4; j++) {
        const int nt = c*4 + j;
        const f32x4 s4 = __builtin_amdgcn_mfma_f32_16x16x32_bf16(kf[j], af, (f32x4)0.f, 0, 0, 0);
        const int tb = nt*16 + l4*4;
        const int sh = tb & 31;
        uintT bits = mww[nt >> 1] >> sh;
        if (src == 0) bits &= adjr[nt >> 1] >> sh;
        const float e0 = (bits & 1u) ? EXP2(s4[0]) : 0.f;
        const float e1 = (bits & 2u) ? EXP2(s4[1]) : 0.f;
        const float e2 = (bits & 4u) ? EXP2(s4[2]) : 0.f;
        const float e3 = (bits & 8u) ? EXP2(s4[3]) : 0.f;
        rsum += (e0 + e1) + (e2 + e3);
        uintT pk01, pk23;
        asm("v_cvt_pk_bf16_f32 %0, %1, %2" : "=v"(pk01) : "v"(e0), "v"(e1));
        asm("v_cvt_pk_bf16_f32 %0, %1, %2" : "=v"(pk23) : "v"(e2), "v"(e3));
        uint2 pw; pw.x = pk01; pw.y = pk23;
        *(uint2*)(Prow + (((uintT)(tb*2)) ^ swz)) = pw;
      }
    }
    rsum += __shfl_xor(rsum, 16, 64);
    rsum += __shfl_xor(rsum, 32, 64);
    const float rv = 1.f / rsum;
    float rvr[4];
    #pragma unroll
    for (int r = 0; r < 4; r++) rvr[r] = __shfl(rv, l4*4 + r, 64);

    f32x4 o0 = (f32x4)0.f, o1 = (f32x4)0.f;
    __builtin_amdgcn_s_setprio(1);
    #pragma unroll
    for (int kt = 0; kt < 8; kt++) {
      const bf16x8 ap = *(const bf16x8*)(Prow + (((uintT)(kt*64 + l4*16)) ^ swz));
      const bf16x8 v0 = *(const bf16x8*)&Vtp[(bh + h*32 + l15) * 256 + kt*32 + l4*8];
      const bf16x8 v1 = *(const bf16x8*)&Vtp[(bh + h*32 + 16 + l15) * 256 + kt*32 + l4*8];
      o0 = __builtin_amdgcn_mfma_f32_16x16x32_bf16(ap, v0, o0, 0, 0, 0);
      o1 = __builtin_amdgcn_mfma_f32_16x16x32_bf16(ap, v1, o1, 0, 0, 0);
    }
    __builtin_amdgcn_s_setprio(0);
    #pragma unroll
    for (int r = 0; r < 4; r++) { acc0[r] += o0[r] * rvr[r]; acc1[r] += o1[r] * rvr[r]; }
  }

  #pragma unroll
  for (int r = 0; r < 4; r++) {
    const int row = (int)(bh + q0 + wave*16 + l4*4 + r);
    QC[(size_t)row * 256 + h*32 + l15]      = f2b(acc0[r]);
    QC[(size_t)row * 256 + h*32 + 16 + l15] = f2b(acc1[r]);
  }
}

// ---------------------------------------------------------------------------
// Orchestration v7 = r14 data path (proven 448.7) + merged prep (10 launches).
//  1. prep (pack adj+masks, Wqkvo -> S5, W1t, W2t)
//  2. conv2: x1 -> S0, x2 -> S2
//  3. KV2 fused: A=S2 -> k2@S3, v2t@S1
//  4. QKV fused: A=S0 -> k1@S2, v1t@S4, q@qbuf
//  5. attn: q@qbuf -> c@qbuf
//  6. proj: c@qbuf x Wot@S5 -> S3
//  7. LN1: x1+S3 -> S0   8. FFN1 -> S1..S4   9. FFN2 -> S5 (pack dead)
// 10. LN2: S0+S5 -> d_out
// ---------------------------------------------------------------------------
extern "C" void kernel_launch(void* const* d_in, const int* in_sizes, int n_in,
                              void* d_out, int out_size, void* d_ws, size_t ws_size,
                              hipStream_t stream) {
  const void* x1    = d_in[0];
  const void* adj1  = d_in[1];
  const void* mask1 = d_in[2];
  const void* x2    = d_in[3];
  const void* mask2 = d_in[4];
  const void* Wq = d_in[5];  const void* bq = d_in[6];
  const void* Wk = d_in[7];  const void* bk = d_in[8];
  const void* Wv = d_in[9];  const void* bv = d_in[10];
  const void* Wo = d_in[11]; const void* bo = d_in[12];
  const void* W1 = d_in[13]; const void* b1 = d_in[14];
  const void* W2 = d_in[15]; const void* b2 = d_in[16];
  const void* g1 = d_in[17]; const void* be1= d_in[18];
  const void* g2 = d_in[19]; const void* be2= d_in[20];
  const ushortT* sniffp = (const ushortT*)x1;

  ushortT* ws = (ushortT*)d_ws;
  const size_t SZ = (size_t)M_ * D_;
  ushortT* S0 = ws;
  ushortT* S1 = ws + SZ;
  ushortT* S2 = ws + 2*SZ;
  ushortT* S3 = ws + 3*SZ;
  ushortT* S4 = ws + 4*SZ;
  ushortT* S5 = ws + 5*SZ;
  ushortT* dOut = (ushortT*)d_out;

  ushortT* Wpack = S5;               // [1024][256]: k|v|q|o
  ushortT* Wot   = S5 + 196608;
  ushortT* W1t = dOut;               // [1024][256] @ dOut 0..512K elems
  ushortT* W2t = dOut + 262144;      // [256][1024] @ 512K..1M elems
  ushortT* qbuf = dOut + 524288;     // q/c scratch (1..17.8 MB)
  uintT* AB = (uintT*)(dOut + 9437184);   // 1 MiB @ +18.9 MB
  uintT* MWp = AB + 262144;               // 2048 words

  const float qalpha = 0.25503486f;  // 1/sqrt(32) * log2(e)

  dim3 blk(256);
  dim3 gGemmD(M_/128, D_/128);       // (256, 2)
  dim3 gGemmF(M_/128, DFF_/128);     // (256, 8)
  dim3 gQKV(M_/128, 6);              // fused k|v|q, N=768
  dim3 gKV(M_/128, 4);               // fused k|v, N=512
  const int nblk1 = (int)(SZ / 8 / 256);   // 4096 blocks per tensor

  // 1) prep: all packs + weight transposes (1 dispatch)
  prep_kernel<<<dim3(1800), blk, 0, stream>>>(
      adj1, AB, mask1, mask2, MWp, Wk, Wv, Wq, Wo, Wpack, W1, W1t, W2, W2t, sniffp);

  // 2) convert x1 -> S0 and x2 -> S2 (1 dispatch)
  conv2_bf16_kernel<<<dim3(2*nblk1), blk, 0, stream>>>(x1, S0, x2, S2, nblk1, sniffp);

  // 3) KV2 fused: k2 -> S3, v2t -> S1
  gemm_qkv_kernel<<<gKV, blk, 0, stream>>>(S2, S5, bk, bv, nullptr,
                                           S3, S1, nullptr, D_, 1.f, sniffp);

  // 4) QKV fused: k1 -> S2, v1t -> S4, q -> qbuf (pre-scaled)
  gemm_qkv_kernel<<<gQKV, blk, 0, stream>>>(S0, S5, bk, bv, bq,
                                            S2, S4, qbuf, D_, qalpha, sniffp);

  // 5) attention: q@qbuf -> c@qbuf ; k1@S2 k2@S3 v1t@S4 v2t@S1
  attn_mfma_kernel<<<dim3(N1_/64, H_, B_), blk, 0, stream>>>(
      qbuf, S2, S3, S4, S1, AB, MWp);

  // 6) proj: c@qbuf x Wot@S5 -> S3
  gemm128_kernel<<<gGemmD, blk, 0, stream>>>(qbuf, Wot, bo, S3, M_, D_, D_, 0, 1.f, sniffp);

  // 7) LN1: x1 + attnp@S3 -> out1@S0
  add_ln_kernel<<<dim3(M_/16), blk, 0, stream>>>(x1, S3, g1, be1, S0, sniffp, 1, 0);

  // 8) FFN1: relu(out1@S0 x W1t^T + b1) -> S1..S4
  gemm128_kernel<<<gGemmF, blk, 0, stream>>>(S0, W1t, b1, S1, M_, DFF_, D_, 1, 1.f, sniffp);

  // 9) FFN2: ffn1@S1 x W2t^T + b2 -> S5
  gemm128_kernel<<<gGemmD, blk, 0, stream>>>(S1, W2t, b2, S5, M_, D_, DFF_, 0, 1.f, sniffp);

  // 10) LN2: out1@S0 + ffn2@S5 -> d_out (f32 fresh write)
  add_ln_kernel<<<dim3(M_/16), blk, 0, stream>>>(S0, S5, g2, be2, d_out, sniffp, 0, 1);
}